// Round 8
// baseline (38.753 us; speedup 1.0000x reference)
//
#include <hip/hip_runtime.h>

#define NJ 24
#define EPSF 1e-10f
#define BLK 256

typedef float v4f __attribute__((ext_vector_type(4)));

// Workspace layout (floats):
//   joint j at offset j*20:
//     [0]=theta [1..3]=w(unit) [4..6]=v/theta [7..9]=w x v [10..12]=(w.v)w
//     [13]=wxx [14]=wyy [15]=wzz [16]=wxy [17]=wxz [18]=wyz [19]=pad
//   T_init rows at offset 480: g0[4], g1[4], g2[4]   (R | p)
#define TI_OFF (NJ * 20)
#define WS_FLOATS (TI_OFF + 12)

__global__ void poe_setup(const float* __restrict__ twist,
                          const float* __restrict__ init_p,
                          const float* __restrict__ init_rpy,
                          float* __restrict__ cb)
{
    const int tid = threadIdx.x;
    if (tid < NJ) {
        const int j = tid;
        float wx = twist[j*6+0], wy = twist[j*6+1], wz = twist[j*6+2];
        float vx = twist[j*6+3], vy = twist[j*6+4], vz = twist[j*6+5];
        float theta = sqrtf(wx*wx + wy*wy + wz*wz) + EPSF;
        float inv = 1.0f / theta;
        wx *= inv; wy *= inv; wz *= inv;
        vx *= inv; vy *= inv; vz *= inv;
        float cx = wy*vz - wz*vy;
        float cy = wz*vx - wx*vz;
        float cz = wx*vy - wy*vx;
        float wdv = wx*vx + wy*vy + wz*vz;
        float* c = cb + j*20;
        c[0]=theta; c[1]=wx; c[2]=wy; c[3]=wz;
        c[4]=vx; c[5]=vy; c[6]=vz;
        c[7]=cx; c[8]=cy; c[9]=cz;
        c[10]=wdv*wx; c[11]=wdv*wy; c[12]=wdv*wz;
        c[13]=wx*wx; c[14]=wy*wy; c[15]=wz*wz;
        c[16]=wx*wy; c[17]=wx*wz; c[18]=wy*wz; c[19]=0.f;
    } else if (tid == 32) {
        float r  = init_rpy[0], pt = init_rpy[1], yw = init_rpy[2];
        float cr = cosf(r),  sr = sinf(r);
        float cp = cosf(pt), sp = sinf(pt);
        float cy = cosf(yw), sy = sinf(yw);
        float* t = cb + TI_OFF;
        t[0]=cy*cp; t[1]=cy*sp*sr - sy*cr; t[2]=cy*sp*cr + sy*sr; t[3]=init_p[0];
        t[4]=sy*cp; t[5]=sy*sp*sr + cy*cr; t[6]=sy*sp*cr - cy*sr; t[7]=init_p[1];
        t[8]=-sp;   t[9]=cp*sr;            t[10]=cp*cr;           t[11]=init_p[2];
    }
}

// One fully-unrolled joint step (identical arithmetic to the 35.9us baseline).
#define JSTEP(J, QJ) { \
    const float* c = cb + (J)*20; \
    const float qt = (QJ) * c[0]; \
    const float s  = __sinf(qt); \
    const float cc = __cosf(qt); \
    const float oc = 1.0f - cc; \
    const float a  = qt - s; \
    const float t1 = s * c[3], t2 = s * c[2], t3 = s * c[1]; \
    const float A00 = fmaf(oc, c[13],  cc); \
    const float A11 = fmaf(oc, c[14],  cc); \
    const float A22 = fmaf(oc, c[15],  cc); \
    const float A01 = fmaf(oc, c[16], -t1); \
    const float A10 = fmaf(oc, c[16],  t1); \
    const float A02 = fmaf(oc, c[17],  t2); \
    const float A20 = fmaf(oc, c[17], -t2); \
    const float A12 = fmaf(oc, c[18], -t3); \
    const float A21 = fmaf(oc, c[18],  t3); \
    const float pjx = fmaf(s, c[4], fmaf(oc, c[7], a * c[10])); \
    const float pjy = fmaf(s, c[5], fmaf(oc, c[8], a * c[11])); \
    const float pjz = fmaf(s, c[6], fmaf(oc, c[9], a * c[12])); \
    px = fmaf(R00, pjx, fmaf(R01, pjy, fmaf(R02, pjz, px))); \
    py = fmaf(R10, pjx, fmaf(R11, pjy, fmaf(R12, pjz, py))); \
    pz = fmaf(R20, pjx, fmaf(R21, pjy, fmaf(R22, pjz, pz))); \
    const float N00 = fmaf(R00, A00, fmaf(R01, A10, R02 * A20)); \
    const float N01 = fmaf(R00, A01, fmaf(R01, A11, R02 * A21)); \
    const float N02 = fmaf(R00, A02, fmaf(R01, A12, R02 * A22)); \
    const float N10 = fmaf(R10, A00, fmaf(R11, A10, R12 * A20)); \
    const float N11 = fmaf(R10, A01, fmaf(R11, A11, R12 * A21)); \
    const float N12 = fmaf(R10, A02, fmaf(R11, A12, R12 * A22)); \
    const float N20 = fmaf(R20, A00, fmaf(R21, A10, R22 * A20)); \
    const float N21 = fmaf(R20, A01, fmaf(R21, A11, R22 * A21)); \
    const float N22 = fmaf(R20, A02, fmaf(R21, A12, R22 * A22)); \
    R00=N00; R01=N01; R02=N02; \
    R10=N10; R11=N11; R12=N12; \
    R20=N20; R21=N21; R22=N22; \
}

// Counted wait: oldest (7-N-? ) vmem ops retired; sched_barrier(0) per rule #18
// keeps hipcc from hoisting register-only uses above the inline-asm waitcnt.
#define QWAIT(N) \
    asm volatile("s_waitcnt vmcnt(" #N ")" ::: "memory"); \
    __builtin_amdgcn_sched_barrier(0);

__global__ __launch_bounds__(BLK, 8) void poe_main(
    const float* __restrict__ q,    // (B, 24)
    const float* __restrict__ cb,   // WS_FLOATS constants (uniform -> s_load)
    float* __restrict__ out,        // (B, 4, 4)
    int B)
{
    const int b = blockIdx.x * BLK + threadIdx.x;
    if (b >= B) return;

    const float* qptr = q + (size_t)b * NJ;
    float* optr = out + (size_t)b * 16;

    // --- issue all 6 q loads via volatile asm: cannot be sunk (fixes the
    // latency-serial "re-sunk loads" pathology) and cannot be duplicated
    // (fixes the 2.5x over-fetch pathology). Issue order defines vmcnt order.
    v4f qa, qb, qc, qd, qe, qf;
    asm volatile("global_load_dwordx4 %0, %1, off"           : "=v"(qa) : "v"(qptr));
    asm volatile("global_load_dwordx4 %0, %1, off offset:16" : "=v"(qb) : "v"(qptr));
    asm volatile("global_load_dwordx4 %0, %1, off offset:32" : "=v"(qc) : "v"(qptr));
    asm volatile("global_load_dwordx4 %0, %1, off offset:48" : "=v"(qd) : "v"(qptr));
    asm volatile("global_load_dwordx4 %0, %1, off offset:64" : "=v"(qe) : "v"(qptr));
    asm volatile("global_load_dwordx4 %0, %1, off offset:80" : "=v"(qf) : "v"(qptr));

    // --- data-independent identity row stored NOW (7th vmem op): moves 25%
    // of the write traffic out of the end-of-kernel store burst.
    {
        v4f r3 = {0.f, 0.f, 0.f, 1.f};
        asm volatile("global_store_dwordx4 %0, %1, off offset:48"
                     :: "v"(optr), "v"(r3) : "memory");
    }

    float R00=1.f, R01=0.f, R02=0.f;
    float R10=0.f, R11=1.f, R12=0.f;
    float R20=0.f, R21=0.f, R22=1.f;
    float px=0.f, py=0.f, pz=0.f;

    // 7 vmem ops outstanding. vmcnt(6) -> oldest (qa) done; vmcnt(5) -> qb; ...
    // Wave starts compute after its FIRST 16B lands; loads 2-6 stream under
    // joints 0-19 instead of draining up-front (the old pin = vmcnt(0) wall).
    QWAIT(6)
    JSTEP(0,  qa.x) JSTEP(1,  qa.y) JSTEP(2,  qa.z) JSTEP(3,  qa.w)
    QWAIT(5)
    JSTEP(4,  qb.x) JSTEP(5,  qb.y) JSTEP(6,  qb.z) JSTEP(7,  qb.w)
    QWAIT(4)
    JSTEP(8,  qc.x) JSTEP(9,  qc.y) JSTEP(10, qc.z) JSTEP(11, qc.w)
    QWAIT(3)
    JSTEP(12, qd.x) JSTEP(13, qd.y) JSTEP(14, qd.z) JSTEP(15, qd.w)
    QWAIT(2)
    JSTEP(16, qe.x) JSTEP(17, qe.y) JSTEP(18, qe.z) JSTEP(19, qe.w)
    QWAIT(1)
    JSTEP(20, qf.x) JSTEP(21, qf.y) JSTEP(22, qf.z) JSTEP(23, qf.w)

    // out = carry @ T_init   (uniform scalar reads)
    const float* t = cb + TI_OFF;
    const float g00=t[0], g01=t[1], g02=t[2], g03=t[3];
    const float g10=t[4], g11=t[5], g12=t[6], g13=t[7];
    const float g20=t[8], g21=t[9], g22=t[10], g23=t[11];

    const float O00 = fmaf(R00, g00, fmaf(R01, g10, R02 * g20));
    const float O01 = fmaf(R00, g01, fmaf(R01, g11, R02 * g21));
    const float O02 = fmaf(R00, g02, fmaf(R01, g12, R02 * g22));
    const float Opx = fmaf(R00, g03, fmaf(R01, g13, fmaf(R02, g23, px)));

    const float O10 = fmaf(R10, g00, fmaf(R11, g10, R12 * g20));
    const float O11 = fmaf(R10, g01, fmaf(R11, g11, R12 * g21));
    const float O12 = fmaf(R10, g02, fmaf(R11, g12, R12 * g22));
    const float Opy = fmaf(R10, g03, fmaf(R11, g13, fmaf(R12, g23, py)));

    const float O20 = fmaf(R20, g00, fmaf(R21, g10, R22 * g20));
    const float O21 = fmaf(R20, g01, fmaf(R21, g11, R22 * g21));
    const float O22 = fmaf(R20, g02, fmaf(R21, g12, R22 * g22));
    const float Opz = fmaf(R20, g03, fmaf(R21, g13, fmaf(R22, g23, pz)));

    v4f* o4 = reinterpret_cast<v4f*>(optr);
    v4f r0 = {O00, O01, O02, Opx};
    v4f r1 = {O10, O11, O12, Opy};
    v4f r2 = {O20, O21, O22, Opz};
    o4[0] = r0;
    o4[1] = r1;
    o4[2] = r2;
    // row 3 already stored up-front
}

#undef JSTEP
#undef QWAIT

extern "C" void kernel_launch(void* const* d_in, const int* in_sizes, int n_in,
                              void* d_out, int out_size, void* d_ws, size_t ws_size,
                              hipStream_t stream) {
    const float* q        = (const float*)d_in[0];
    const float* twist    = (const float*)d_in[1];
    const float* init_p   = (const float*)d_in[2];
    const float* init_rpy = (const float*)d_in[3];
    float* out            = (float*)d_out;
    float* cb             = (float*)d_ws;   // needs WS_FLOATS*4 = 1968 bytes

    const int B = in_sizes[0] / NJ;
    const int blocks = (B + BLK - 1) / BLK;

    poe_setup<<<1, 64, 0, stream>>>(twist, init_p, init_rpy, cb);
    poe_main<<<blocks, BLK, 0, stream>>>(q, cb, out, B);
}

// Round 9
// 36.039 us; speedup vs baseline: 1.0753x; 1.0753x over previous
//
#include <hip/hip_runtime.h>

#define NJ 24
#define EPSF 1e-10f
#define BLK 256

// Workspace layout (floats):
//   joint j at offset j*20:
//     [0]=theta [1..3]=w(unit) [4..6]=v/theta [7..9]=w x v [10..12]=(w.v)w
//     [13]=wxx [14]=wyy [15]=wzz [16]=wxy [17]=wxz [18]=wyz [19]=pad
//   T_init rows at offset 480: g0[4], g1[4], g2[4]   (R | p)
#define TI_OFF (NJ * 20)
#define WS_FLOATS (TI_OFF + 12)

__global__ void poe_setup(const float* __restrict__ twist,
                          const float* __restrict__ init_p,
                          const float* __restrict__ init_rpy,
                          float* __restrict__ cb)
{
    const int tid = threadIdx.x;
    if (tid < NJ) {
        const int j = tid;
        float wx = twist[j*6+0], wy = twist[j*6+1], wz = twist[j*6+2];
        float vx = twist[j*6+3], vy = twist[j*6+4], vz = twist[j*6+5];
        float theta = sqrtf(wx*wx + wy*wy + wz*wz) + EPSF;
        float inv = 1.0f / theta;
        wx *= inv; wy *= inv; wz *= inv;
        vx *= inv; vy *= inv; vz *= inv;
        float cx = wy*vz - wz*vy;
        float cy = wz*vx - wx*vz;
        float cz = wx*vy - wy*vx;
        float wdv = wx*vx + wy*vy + wz*vz;
        float* c = cb + j*20;
        c[0]=theta; c[1]=wx; c[2]=wy; c[3]=wz;
        c[4]=vx; c[5]=vy; c[6]=vz;
        c[7]=cx; c[8]=cy; c[9]=cz;
        c[10]=wdv*wx; c[11]=wdv*wy; c[12]=wdv*wz;
        c[13]=wx*wx; c[14]=wy*wy; c[15]=wz*wz;
        c[16]=wx*wy; c[17]=wx*wz; c[18]=wy*wz; c[19]=0.f;
    } else if (tid == 32) {
        float r  = init_rpy[0], pt = init_rpy[1], yw = init_rpy[2];
        float cr = cosf(r),  sr = sinf(r);
        float cp = cosf(pt), sp = sinf(pt);
        float cy = cosf(yw), sy = sinf(yw);
        float* t = cb + TI_OFF;
        t[0]=cy*cp; t[1]=cy*sp*sr - sy*cr; t[2]=cy*sp*cr + sy*sr; t[3]=init_p[0];
        t[4]=sy*cp; t[5]=sy*sp*sr + cy*cr; t[6]=sy*sp*cr - cy*sr; t[7]=init_p[1];
        t[8]=-sp;   t[9]=cp*sr;            t[10]=cp*cr;           t[11]=init_p[2];
    }
}

// ---- double-banked scalar-constant software pipeline ----
// JLOAD issues the 19 uniform s_loads for joint J into bank P (named scalar
// variables -> SGPRs), one joint ahead of use.
#define JLOAD(P, J) { \
    const float* c = cb + (J)*20; \
    P##0 = c[0];  P##1 = c[1];  P##2 = c[2];  P##3 = c[3];  P##4 = c[4]; \
    P##5 = c[5];  P##6 = c[6];  P##7 = c[7];  P##8 = c[8];  P##9 = c[9]; \
    P##10 = c[10]; P##11 = c[11]; P##12 = c[12]; P##13 = c[13]; P##14 = c[14]; \
    P##15 = c[15]; P##16 = c[16]; P##17 = c[17]; P##18 = c[18]; \
}

// One joint step using bank P (same arithmetic/rounding as the baseline).
#define JCOMP(P, QJ) { \
    const float qt = (QJ) * P##0; \
    const float s  = __sinf(qt); \
    const float cc = __cosf(qt); \
    const float oc = 1.0f - cc; \
    const float a  = qt - s; \
    const float t1 = s * P##3, t2 = s * P##2, t3 = s * P##1; \
    const float A00 = fmaf(oc, P##13,  cc); \
    const float A11 = fmaf(oc, P##14,  cc); \
    const float A22 = fmaf(oc, P##15,  cc); \
    const float A01 = fmaf(oc, P##16, -t1); \
    const float A10 = fmaf(oc, P##16,  t1); \
    const float A02 = fmaf(oc, P##17,  t2); \
    const float A20 = fmaf(oc, P##17, -t2); \
    const float A12 = fmaf(oc, P##18, -t3); \
    const float A21 = fmaf(oc, P##18,  t3); \
    const float pjx = fmaf(s, P##4, fmaf(oc, P##7, a * P##10)); \
    const float pjy = fmaf(s, P##5, fmaf(oc, P##8, a * P##11)); \
    const float pjz = fmaf(s, P##6, fmaf(oc, P##9, a * P##12)); \
    px = fmaf(R00, pjx, fmaf(R01, pjy, fmaf(R02, pjz, px))); \
    py = fmaf(R10, pjx, fmaf(R11, pjy, fmaf(R12, pjz, py))); \
    pz = fmaf(R20, pjx, fmaf(R21, pjy, fmaf(R22, pjz, pz))); \
    const float N00 = fmaf(R00, A00, fmaf(R01, A10, R02 * A20)); \
    const float N01 = fmaf(R00, A01, fmaf(R01, A11, R02 * A21)); \
    const float N02 = fmaf(R00, A02, fmaf(R01, A12, R02 * A22)); \
    const float N10 = fmaf(R10, A00, fmaf(R11, A10, R12 * A20)); \
    const float N11 = fmaf(R10, A01, fmaf(R11, A11, R12 * A21)); \
    const float N12 = fmaf(R10, A02, fmaf(R11, A12, R12 * A22)); \
    const float N20 = fmaf(R20, A00, fmaf(R21, A10, R22 * A20)); \
    const float N21 = fmaf(R20, A01, fmaf(R21, A11, R22 * A21)); \
    const float N22 = fmaf(R20, A02, fmaf(R21, A12, R22 * A22)); \
    R00=N00; R01=N01; R02=N02; \
    R10=N10; R11=N11; R12=N12; \
    R20=N20; R21=N21; R22=N22; \
}

__global__ __launch_bounds__(BLK) void poe_main(
    const float* __restrict__ q,    // (B, 24)
    const float* __restrict__ cb,   // WS_FLOATS constants (uniform -> s_load)
    float* __restrict__ out,        // (B, 4, 4)
    int B)
{
    const int b = blockIdx.x * BLK + threadIdx.x;
    if (b >= B) return;

    const float4* qp = reinterpret_cast<const float4*>(q + (size_t)b * NJ);

    // All 24 q values in NAMED registers, pinned (rule #20 / anti-over-fetch).
    float4 qa = qp[0], qb = qp[1], qc = qp[2], qd = qp[3], qe = qp[4], qf = qp[5];
    asm volatile("" : "+v"(qa.x), "+v"(qa.y), "+v"(qa.z), "+v"(qa.w),
                      "+v"(qb.x), "+v"(qb.y), "+v"(qb.z), "+v"(qb.w),
                      "+v"(qc.x), "+v"(qc.y), "+v"(qc.z), "+v"(qc.w));
    asm volatile("" : "+v"(qd.x), "+v"(qd.y), "+v"(qd.z), "+v"(qd.w),
                      "+v"(qe.x), "+v"(qe.y), "+v"(qe.z), "+v"(qe.w),
                      "+v"(qf.x), "+v"(qf.y), "+v"(qf.z), "+v"(qf.w));

    float R00=1.f, R01=0.f, R02=0.f;
    float R10=0.f, R11=1.f, R12=0.f;
    float R20=0.f, R21=0.f, R22=1.f;
    float px=0.f, py=0.f, pz=0.f;

    // Two constant banks (19 scalars each -> SGPRs).
    float ka0,ka1,ka2,ka3,ka4,ka5,ka6,ka7,ka8,ka9,
          ka10,ka11,ka12,ka13,ka14,ka15,ka16,ka17,ka18;
    float kb0,kb1,kb2,kb3,kb4,kb5,kb6,kb7,kb8,kb9,
          kb10,kb11,kb12,kb13,kb14,kb15,kb16,kb17,kb18;

    // Prologue: joints 0 and 1 in flight before any compute.
    JLOAD(ka, 0) JLOAD(kb, 1)

    // Steady state: compute joint j from its bank, immediately refill that
    // bank with joint j+2.
    JCOMP(ka, qa.x) JLOAD(ka, 2)
    JCOMP(kb, qa.y) JLOAD(kb, 3)
    JCOMP(ka, qa.z) JLOAD(ka, 4)
    JCOMP(kb, qa.w) JLOAD(kb, 5)
    JCOMP(ka, qb.x) JLOAD(ka, 6)
    JCOMP(kb, qb.y) JLOAD(kb, 7)
    JCOMP(ka, qb.z) JLOAD(ka, 8)
    JCOMP(kb, qb.w) JLOAD(kb, 9)
    JCOMP(ka, qc.x) JLOAD(ka, 10)
    JCOMP(kb, qc.y) JLOAD(kb, 11)
    JCOMP(ka, qc.z) JLOAD(ka, 12)
    JCOMP(kb, qc.w) JLOAD(kb, 13)
    JCOMP(ka, qd.x) JLOAD(ka, 14)
    JCOMP(kb, qd.y) JLOAD(kb, 15)
    JCOMP(ka, qd.z) JLOAD(ka, 16)
    JCOMP(kb, qd.w) JLOAD(kb, 17)
    JCOMP(ka, qe.x) JLOAD(ka, 18)
    JCOMP(kb, qe.y) JLOAD(kb, 19)
    JCOMP(ka, qe.z) JLOAD(ka, 20)
    JCOMP(kb, qe.w) JLOAD(kb, 21)
    JCOMP(ka, qf.x) JLOAD(ka, 22)
    JCOMP(kb, qf.y) JLOAD(kb, 23)
    JCOMP(ka, qf.z)
    JCOMP(kb, qf.w)

    // out = carry @ T_init   (uniform scalar reads)
    const float* t = cb + TI_OFF;
    const float g00=t[0], g01=t[1], g02=t[2], g03=t[3];
    const float g10=t[4], g11=t[5], g12=t[6], g13=t[7];
    const float g20=t[8], g21=t[9], g22=t[10], g23=t[11];

    const float O00 = fmaf(R00, g00, fmaf(R01, g10, R02 * g20));
    const float O01 = fmaf(R00, g01, fmaf(R01, g11, R02 * g21));
    const float O02 = fmaf(R00, g02, fmaf(R01, g12, R02 * g22));
    const float Opx = fmaf(R00, g03, fmaf(R01, g13, fmaf(R02, g23, px)));

    const float O10 = fmaf(R10, g00, fmaf(R11, g10, R12 * g20));
    const float O11 = fmaf(R10, g01, fmaf(R11, g11, R12 * g21));
    const float O12 = fmaf(R10, g02, fmaf(R11, g12, R12 * g22));
    const float Opy = fmaf(R10, g03, fmaf(R11, g13, fmaf(R12, g23, py)));

    const float O20 = fmaf(R20, g00, fmaf(R21, g10, R22 * g20));
    const float O21 = fmaf(R20, g01, fmaf(R21, g11, R22 * g21));
    const float O22 = fmaf(R20, g02, fmaf(R21, g12, R22 * g22));
    const float Opz = fmaf(R20, g03, fmaf(R21, g13, fmaf(R22, g23, pz)));

    float4* o4 = reinterpret_cast<float4*>(out + (size_t)b * 16);
    o4[0] = make_float4(O00, O01, O02, Opx);
    o4[1] = make_float4(O10, O11, O12, Opy);
    o4[2] = make_float4(O20, O21, O22, Opz);
    o4[3] = make_float4(0.f, 0.f, 0.f, 1.f);
}

#undef JLOAD
#undef JCOMP

extern "C" void kernel_launch(void* const* d_in, const int* in_sizes, int n_in,
                              void* d_out, int out_size, void* d_ws, size_t ws_size,
                              hipStream_t stream) {
    const float* q        = (const float*)d_in[0];
    const float* twist    = (const float*)d_in[1];
    const float* init_p   = (const float*)d_in[2];
    const float* init_rpy = (const float*)d_in[3];
    float* out            = (float*)d_out;
    float* cb             = (float*)d_ws;   // needs WS_FLOATS*4 = 1968 bytes

    const int B = in_sizes[0] / NJ;
    const int blocks = (B + BLK - 1) / BLK;

    poe_setup<<<1, 64, 0, stream>>>(twist, init_p, init_rpy, cb);
    poe_main<<<blocks, BLK, 0, stream>>>(q, cb, out, B);
}